// Round 2
// baseline (99.784 us; speedup 1.0000x reference)
//
#include <hip/hip_runtime.h>

#define S 32
#define E 48
#define H 512
#define L 16

// ws layout (floats):
//   [0, S*E*L)            ha : 2*a[s,e,l]
//   [S*E*L, 2*S*E*L)      hb : 2*b[s,e,l] + bias[l] - p2[l]
//   [2*S*E*L, 2*S*E*L+L)  stat: bias[l] - p2[l]

__global__ __launch_bounds__(256) void k0_stats(const float* __restrict__ proto,
                                                const float* __restrict__ ic,
                                                float* __restrict__ stat) {
    __shared__ float part[L][16];
    __shared__ float ics[L];
    int t = threadIdx.x;          // 256 threads: l = t>>4, chunk c = t&15
    int l = t >> 4, c = t & 15;
    const float* p = proto + l * (2 * H) + c * 64;
    float acc = 0.f;
#pragma unroll
    for (int k = 0; k < 64; k += 4) {
        float4 v = *reinterpret_cast<const float4*>(p + k);
        acc += v.x * v.x + v.y * v.y + v.z * v.z + v.w * v.w;
    }
    part[l][c] = acc;
    if (t < L) ics[t] = ic[t];
    __syncthreads();
    if (t < L) {
        float p2 = 0.f;
#pragma unroll
        for (int k = 0; k < 16; ++k) p2 += part[t][k];
        float total = 0.f;
#pragma unroll
        for (int k = 0; k < 16; ++k) total += ics[k];
        float bias = ics[t] / (total - ics[t]);
        stat[t] = bias - p2;
    }
}

__global__ __launch_bounds__(64) void k1_dots(const float* __restrict__ emb,
                                              const float* __restrict__ proto,
                                              const float* __restrict__ stat,
                                              float* __restrict__ ha,
                                              float* __restrict__ hb) {
    int se = blockIdx.x;          // 0 .. S*E-1
    int lane = threadIdx.x;       // 0 .. 63
    const float* er = emb + se * H;
    // lane holds h in {4*lane..4*lane+3} and {256+4*lane..+3}
    float4 e0 = *reinterpret_cast<const float4*>(er + 4 * lane);
    float4 e1 = *reinterpret_cast<const float4*>(er + 256 + 4 * lane);

    float my_a = 0.f, my_b = 0.f;
#pragma unroll
    for (int l = 0; l < L; ++l) {
        const float* ph = proto + l * (2 * H);       // head [0,512)
        const float* pt = ph + H;                    // tail [512,1024)
        float4 h0 = *reinterpret_cast<const float4*>(ph + 4 * lane);
        float4 h1 = *reinterpret_cast<const float4*>(ph + 256 + 4 * lane);
        float4 t0 = *reinterpret_cast<const float4*>(pt + 4 * lane);
        float4 t1 = *reinterpret_cast<const float4*>(pt + 256 + 4 * lane);
        float da = e0.x * h0.x + e0.y * h0.y + e0.z * h0.z + e0.w * h0.w
                 + e1.x * h1.x + e1.y * h1.y + e1.z * h1.z + e1.w * h1.w;
        float db = e0.x * t0.x + e0.y * t0.y + e0.z * t0.z + e0.w * t0.w
                 + e1.x * t1.x + e1.y * t1.y + e1.z * t1.z + e1.w * t1.w;
#pragma unroll
        for (int m = 32; m >= 1; m >>= 1) {
            da += __shfl_xor(da, m);
            db += __shfl_xor(db, m);
        }
        if (lane == l) { my_a = da; my_b = db; }   // lane l keeps result for l
    }
    if (lane < L) {
        ha[se * L + lane] = 2.f * my_a;
        hb[se * L + lane] = 2.f * my_b + stat[lane];
    }
}

// one wave per (s,e1,e2) output row; 4 waves per block
__global__ __launch_bounds__(256) void k2_softmax(const float* __restrict__ ha,
                                                  const float* __restrict__ hb,
                                                  float* __restrict__ out) {
    int wid = threadIdx.x >> 6;
    int lane = threadIdx.x & 63;
    int r = blockIdx.x * 4 + wid;          // row id, < S*E*E = 73728
    int s = r / (E * E);
    int rem = r - s * (E * E);
    int e1 = rem / E;
    int e2 = rem - e1 * E;

    float4 v;
    if (e1 == e2) {
        v = make_float4(0.f, 0.f, 0.f, 0.f);   // diagonal: pred forced to 0
    } else {
        int l16 = lane & 15;
        float logit = ha[(s * E + e1) * L + l16] + hb[(s * E + e2) * L + l16];
        float m = logit;
        m = fmaxf(m, __shfl_xor(m, 1));
        m = fmaxf(m, __shfl_xor(m, 2));
        m = fmaxf(m, __shfl_xor(m, 4));
        m = fmaxf(m, __shfl_xor(m, 8));
        float ex = __expf(logit - m);
        float sum = ex;
        sum += __shfl_xor(sum, 1);
        sum += __shfl_xor(sum, 2);
        sum += __shfl_xor(sum, 4);
        sum += __shfl_xor(sum, 8);
        float pred = ex / sum;
        // lane writes out[l1,l2] for flat positions 4*lane..4*lane+3 (mod-16 = l2)
        int base = lane & 48;
        v.x = __shfl(pred, base | ((4 * lane + 0) & 15));
        v.y = __shfl(pred, base | ((4 * lane + 1) & 15));
        v.z = __shfl(pred, base | ((4 * lane + 2) & 15));
        v.w = __shfl(pred, base | ((4 * lane + 3) & 15));
    }
    reinterpret_cast<float4*>(out)[(size_t)r * 64 + lane] = v;
}

extern "C" void kernel_launch(void* const* d_in, const int* in_sizes, int n_in,
                              void* d_out, int out_size, void* d_ws, size_t ws_size,
                              hipStream_t stream) {
    const float* emb   = (const float*)d_in[0];   // (S,E,H)
    const float* proto = (const float*)d_in[1];   // (L,2H)
    const float* ic    = (const float*)d_in[2];   // (L,)
    float* out = (float*)d_out;

    float* ws   = (float*)d_ws;
    float* ha   = ws;
    float* hb   = ws + S * E * L;
    float* stat = ws + 2 * S * E * L;

    k0_stats<<<1, 256, 0, stream>>>(proto, ic, stat);
    k1_dots<<<S * E, 64, 0, stream>>>(emb, proto, stat, ha, hb);
    k2_softmax<<<(S * E * E) / 4, 256, 0, stream>>>(ha, hb, out);
}

// Round 3
// 98.811 us; speedup vs baseline: 1.0098x; 1.0098x over previous
//
#include <hip/hip_runtime.h>

#define S 32
#define E 48
#define H 512
#define L 16

// ws layout (floats):
//   [0, S*E*L)            ha : 2*a[s,e,l]
//   [S*E*L, 2*S*E*L)      hb : 2*b[s,e,l] + bias[l] - p2[l]
//   [2*S*E*L, 2*S*E*L+L)  stat: bias[l] - p2[l]

__global__ __launch_bounds__(256) void k0_stats(const float* __restrict__ proto,
                                                const float* __restrict__ ic,
                                                float* __restrict__ stat) {
    __shared__ float part[L][16];
    __shared__ float ics[L];
    int t = threadIdx.x;          // 256 threads: l = t>>4, chunk c = t&15
    int l = t >> 4, c = t & 15;
    const float* p = proto + l * (2 * H) + c * 64;
    float acc = 0.f;
#pragma unroll
    for (int k = 0; k < 64; k += 4) {
        float4 v = *reinterpret_cast<const float4*>(p + k);
        acc += v.x * v.x + v.y * v.y + v.z * v.z + v.w * v.w;
    }
    part[l][c] = acc;
    if (t < L) ics[t] = ic[t];
    __syncthreads();
    if (t < L) {
        float p2 = 0.f;
#pragma unroll
        for (int k = 0; k < 16; ++k) p2 += part[t][k];
        float total = 0.f;
#pragma unroll
        for (int k = 0; k < 16; ++k) total += ics[k];
        float bias = ics[t] / (total - ics[t]);
        stat[t] = bias - p2;
    }
}

__global__ __launch_bounds__(64) void k1_dots(const float* __restrict__ emb,
                                              const float* __restrict__ proto,
                                              const float* __restrict__ stat,
                                              float* __restrict__ ha,
                                              float* __restrict__ hb) {
    int se = blockIdx.x;          // 0 .. S*E-1
    int lane = threadIdx.x;       // 0 .. 63
    const float* er = emb + se * H;
    float4 e0 = *reinterpret_cast<const float4*>(er + 4 * lane);
    float4 e1 = *reinterpret_cast<const float4*>(er + 256 + 4 * lane);

    float my_a = 0.f, my_b = 0.f;
#pragma unroll
    for (int l = 0; l < L; ++l) {
        const float* ph = proto + l * (2 * H);       // head [0,512)
        const float* pt = ph + H;                    // tail [512,1024)
        float4 h0 = *reinterpret_cast<const float4*>(ph + 4 * lane);
        float4 h1 = *reinterpret_cast<const float4*>(ph + 256 + 4 * lane);
        float4 t0 = *reinterpret_cast<const float4*>(pt + 4 * lane);
        float4 t1 = *reinterpret_cast<const float4*>(pt + 256 + 4 * lane);
        float da = e0.x * h0.x + e0.y * h0.y + e0.z * h0.z + e0.w * h0.w
                 + e1.x * h1.x + e1.y * h1.y + e1.z * h1.z + e1.w * h1.w;
        float db = e0.x * t0.x + e0.y * t0.y + e0.z * t0.z + e0.w * t0.w
                 + e1.x * t1.x + e1.y * t1.y + e1.z * t1.z + e1.w * t1.w;
#pragma unroll
        for (int m = 32; m >= 1; m >>= 1) {
            da += __shfl_xor(da, m);
            db += __shfl_xor(db, m);
        }
        if (lane == l) { my_a = da; my_b = db; }
    }
    if (lane < L) {
        ha[se * L + lane] = 2.f * my_a;
        hb[se * L + lane] = 2.f * my_b + stat[lane];
    }
}

// one block per (s,e1): compute 48 softmax rows in-register, stream 48KB out
__global__ __launch_bounds__(256) void k2_softmax(const float* __restrict__ ha,
                                                  const float* __restrict__ hb,
                                                  float* __restrict__ out) {
    int e1 = blockIdx.x;          // 0..47
    int s  = blockIdx.y;          // 0..31
    int t  = threadIdx.x;

    __shared__ float hs[L];            // ha row for (s,e1)
    __shared__ float hbL[E][L];        // hb panel for s (48 x 16)
    __shared__ float pred[E][L];       // softmax rows

    if (t < L) hs[t] = ha[(s * E + e1) * L + t];
    if (t < (E * L) / 4) {             // 192 float4 loads, contiguous
        float4 v = reinterpret_cast<const float4*>(hb + (size_t)s * E * L)[t];
        reinterpret_cast<float4*>(&hbL[0][0])[t] = v;
    }
    __syncthreads();

    if (t < E) {                       // thread t owns softmax row e2 = t
        float lg[L];
        float m = -1e30f;
#pragma unroll
        for (int l = 0; l < L; ++l) {
            lg[l] = hs[l] + hbL[t][l];
            m = fmaxf(m, lg[l]);
        }
        float sum = 0.f;
#pragma unroll
        for (int l = 0; l < L; ++l) {
            lg[l] = __expf(lg[l] - m);
            sum += lg[l];
        }
        float inv = (t == e1) ? 0.f : 1.f / sum;   // diagonal -> zero row
#pragma unroll
        for (int l = 0; l < L; ++l) pred[t][l] = lg[l] * inv;
    }
    __syncthreads();

    // (s,e1) owns 48 output rows x 256 floats = 3072 float4s, contiguous
    float4* o4 = reinterpret_cast<float4*>(out) + (size_t)(s * E + e1) * E * 64;
#pragma unroll
    for (int j = 0; j < 12; ++j) {
        int idx4 = j * 256 + t;
        int row = idx4 >> 6;                       // wave-uniform
        const float4* p4 = reinterpret_cast<const float4*>(&pred[row][0]) + (idx4 & 3);
        o4[idx4] = *p4;
    }
}

extern "C" void kernel_launch(void* const* d_in, const int* in_sizes, int n_in,
                              void* d_out, int out_size, void* d_ws, size_t ws_size,
                              hipStream_t stream) {
    const float* emb   = (const float*)d_in[0];   // (S,E,H)
    const float* proto = (const float*)d_in[1];   // (L,2H)
    const float* ic    = (const float*)d_in[2];   // (L,)
    float* out = (float*)d_out;

    float* ws   = (float*)d_ws;
    float* ha   = ws;
    float* hb   = ws + S * E * L;
    float* stat = ws + 2 * S * E * L;

    k0_stats<<<1, 256, 0, stream>>>(proto, ic, stat);
    k1_dots<<<S * E, 64, 0, stream>>>(emb, proto, stat, ha, hb);
    dim3 g2(E, S);
    k2_softmax<<<g2, 256, 0, stream>>>(ha, hb, out);
}

// Round 4
// 94.924 us; speedup vs baseline: 1.0512x; 1.0409x over previous
//
#include <hip/hip_runtime.h>

#define S 32
#define E 48
#define H 512
#define L 16

// ws layout (floats):
//   [0, S*E*L)        ha : 2*a[s,e,l]
//   [S*E*L, 2*S*E*L)  hb : 2*b[s,e,l] + bias[l] - p2[l]

// Fused stats + dots: 4 waves/block, wave w owns l = 4w..4w+3.
__global__ __launch_bounds__(256) void k1_fused(const float* __restrict__ emb,
                                                const float* __restrict__ proto,
                                                const float* __restrict__ ic,
                                                float* __restrict__ ha,
                                                float* __restrict__ hb) {
    int se   = blockIdx.x;         // 0 .. S*E-1
    int t    = threadIdx.x;
    int wid  = t >> 6;             // 0..3
    int lane = t & 63;

    const float* er = emb + (size_t)se * H;
    float4 e0 = *reinterpret_cast<const float4*>(er + 4 * lane);
    float4 e1 = *reinterpret_cast<const float4*>(er + 256 + 4 * lane);

    float my_a = 0.f, my_b = 0.f, my_p = 0.f;
#pragma unroll
    for (int i = 0; i < 4; ++i) {
        int l = wid * 4 + i;
        const float* ph = proto + (size_t)l * (2 * H);   // head [0,512)
        const float* pt = ph + H;                        // tail [512,1024)
        float4 h0 = *reinterpret_cast<const float4*>(ph + 4 * lane);
        float4 h1 = *reinterpret_cast<const float4*>(ph + 256 + 4 * lane);
        float4 t0 = *reinterpret_cast<const float4*>(pt + 4 * lane);
        float4 t1 = *reinterpret_cast<const float4*>(pt + 256 + 4 * lane);
        float da = e0.x * h0.x + e0.y * h0.y + e0.z * h0.z + e0.w * h0.w
                 + e1.x * h1.x + e1.y * h1.y + e1.z * h1.z + e1.w * h1.w;
        float db = e0.x * t0.x + e0.y * t0.y + e0.z * t0.z + e0.w * t0.w
                 + e1.x * t1.x + e1.y * t1.y + e1.z * t1.z + e1.w * t1.w;
        float dp = h0.x * h0.x + h0.y * h0.y + h0.z * h0.z + h0.w * h0.w
                 + h1.x * h1.x + h1.y * h1.y + h1.z * h1.z + h1.w * h1.w
                 + t0.x * t0.x + t0.y * t0.y + t0.z * t0.z + t0.w * t0.w
                 + t1.x * t1.x + t1.y * t1.y + t1.z * t1.z + t1.w * t1.w;
#pragma unroll
        for (int m = 32; m >= 1; m >>= 1) {
            da += __shfl_xor(da, m);
            db += __shfl_xor(db, m);
            dp += __shfl_xor(dp, m);
        }
        if (lane == i) { my_a = da; my_b = db; my_p = dp; }
    }

    if (lane < 4) {
        int l = wid * 4 + lane;
        float total = 0.f;
#pragma unroll
        for (int k = 0; k < L; ++k) total += ic[k];
        float icl  = ic[l];
        float bias = icl / (total - icl);
        ha[(size_t)se * L + l] = 2.f * my_a;
        hb[(size_t)se * L + l] = 2.f * my_b + bias - my_p;
    }
}

// one block per (s,e1): compute 48 softmax rows in-register, stream 48KB out
__global__ __launch_bounds__(256) void k2_softmax(const float* __restrict__ ha,
                                                  const float* __restrict__ hb,
                                                  float* __restrict__ out) {
    int e1 = blockIdx.x;          // 0..47
    int s  = blockIdx.y;          // 0..31
    int t  = threadIdx.x;

    __shared__ float hs[L];            // ha row for (s,e1)
    __shared__ float hbL[E][L];        // hb panel for s (48 x 16)
    __shared__ float pred[E][L];       // softmax rows

    if (t < L) hs[t] = ha[(s * E + e1) * L + t];
    if (t < (E * L) / 4) {             // 192 float4 loads, contiguous
        float4 v = reinterpret_cast<const float4*>(hb + (size_t)s * E * L)[t];
        reinterpret_cast<float4*>(&hbL[0][0])[t] = v;
    }
    __syncthreads();

    if (t < E) {                       // thread t owns softmax row e2 = t
        float lg[L];
        float m = -1e30f;
#pragma unroll
        for (int l = 0; l < L; ++l) {
            lg[l] = hs[l] + hbL[t][l];
            m = fmaxf(m, lg[l]);
        }
        float sum = 0.f;
#pragma unroll
        for (int l = 0; l < L; ++l) {
            lg[l] = __expf(lg[l] - m);
            sum += lg[l];
        }
        float inv = (t == e1) ? 0.f : 1.f / sum;   // diagonal -> zero row
#pragma unroll
        for (int l = 0; l < L; ++l) pred[t][l] = lg[l] * inv;
    }
    __syncthreads();

    // (s,e1) owns 48 output rows x 256 floats = 3072 float4s, contiguous
    float4* o4 = reinterpret_cast<float4*>(out) + (size_t)(s * E + e1) * E * 64;
#pragma unroll
    for (int j = 0; j < 12; ++j) {
        int idx4 = j * 256 + t;
        int row = idx4 >> 6;                       // wave-uniform
        const float4* p4 = reinterpret_cast<const float4*>(&pred[row][0]) + (idx4 & 3);
        o4[idx4] = *p4;
    }
}

extern "C" void kernel_launch(void* const* d_in, const int* in_sizes, int n_in,
                              void* d_out, int out_size, void* d_ws, size_t ws_size,
                              hipStream_t stream) {
    const float* emb   = (const float*)d_in[0];   // (S,E,H)
    const float* proto = (const float*)d_in[1];   // (L,2H)
    const float* ic    = (const float*)d_in[2];   // (L,)
    float* out = (float*)d_out;

    float* ws = (float*)d_ws;
    float* ha = ws;
    float* hb = ws + S * E * L;

    k1_fused<<<S * E, 256, 0, stream>>>(emb, proto, ic, ha, hb);
    dim3 g2(E, S);
    k2_softmax<<<g2, 256, 0, stream>>>(ha, hb, out);
}